// Round 9
// baseline (41.536 us; speedup 1.0000x reference)
//
#include <hip/hip_runtime.h>
#include <hip/hip_bf16.h>

// out[8192,1024] = x[8192,1024] @ W[1024,1024]^T + b  (fp32 in/out, bf16 MFMA)
// v9: TWO kernels.
//  1) cvt_stage: x,W f32 -> bf16 into d_ws, pre-tiled in GEMM fragment order
//     (tile [128 rows][32 k], 16-row stripes of 1024B, slot = kq*256+r16*16).
//  2) gemm_dma: 128x128 tile, BK=32, 256 thr / 4 waves (2x2, wave 64x64),
//     global_load_lds width-16 DMA staging (linear LDS = linear global, no cvt,
//     no reg roundtrip), TRIPLE-buffered LDS (48KB -> 2 blocks/CU), counted
//     vmcnt(4) + raw s_barrier (never drained in-loop), XCD-exclusive m-panels.

typedef float f32x4 __attribute__((ext_vector_type(4)));
typedef __bf16 bf16x8 __attribute__((ext_vector_type(8)));
typedef unsigned short u16x8 __attribute__((ext_vector_type(8)));

#define MD 8192
#define ND 1024
#define KD 1024
#define BM 128
#define BN 128
#define BK 32
#define NT (KD / BK)                 // 32 K-tiles
#define XSLOTS ((MD * KD) / 8)       // 1048576 16B-slots for x
#define WSLOTS ((ND * KD) / 8)       // 131072 for W
#define WOFF   ((size_t)MD * KD * 2) // 16 MB: W area offset in ws
#define WS_NEEDED (WOFF + (size_t)ND * KD * 2)  // 18874368 B

// ---------------- kernel 1: f32 -> bf16 fragment-tiled staging ----------------
__global__ __launch_bounds__(256)
void cvt_stage(const float* __restrict__ X, const float* __restrict__ W,
               unsigned char* __restrict__ ws) {
  const int i = blockIdx.x * 256 + threadIdx.x;   // grid sized exactly
  const float* src;
  size_t obyte;
  if (i < XSLOTS) {
    const int row = i >> 7, k8 = i & 127;         // 128 slots per row (K/8)
    src = X + (size_t)row * KD + k8 * 8;
    const int mt = row >> 7, st = (row >> 4) & 7, r16 = row & 15;
    const int kt = k8 >> 2, kq = k8 & 3;
    obyte = (size_t)(mt * 32 + kt) * 8192 + st * 1024 + kq * 256 + r16 * 16;
  } else {
    const int j = i - XSLOTS;
    const int row = j >> 7, k8 = j & 127;
    src = W + (size_t)row * KD + k8 * 8;
    const int nt = row >> 7, st = (row >> 4) & 7, r16 = row & 15;
    const int kt = k8 >> 2, kq = k8 & 3;
    obyte = WOFF + (size_t)(nt * 32 + kt) * 8192 + st * 1024 + kq * 256 + r16 * 16;
  }
  f32x4 lo = *(const f32x4*)src;
  f32x4 hi = *(const f32x4*)(src + 4);
  u16x8 o;
#pragma unroll
  for (int j = 0; j < 4; ++j) {
    o[j]     = __builtin_bit_cast(unsigned short, (__bf16)lo[j]);
    o[4 + j] = __builtin_bit_cast(unsigned short, (__bf16)hi[j]);
  }
  *(u16x8*)(ws + obyte) = o;
}

// ---------------- kernel 2: DMA-staged bf16 GEMM ----------------
__device__ __forceinline__ void dma16(const void* g, void* l) {
  __builtin_amdgcn_global_load_lds(
      (const __attribute__((address_space(1))) unsigned int*)g,
      (__attribute__((address_space(3))) unsigned int*)l, 16, 0, 0);
}

__global__ __launch_bounds__(256, 2)
void gemm_dma(const unsigned char* __restrict__ ws, const float* __restrict__ Bv,
              float* __restrict__ C) {
  // [stage][A=0/B=1][8192 B]; tile image identical to global staged layout.
  __shared__ __align__(16) unsigned char Lds[3][2][8192];   // 48 KB

  const int bid = blockIdx.x;
  const int xcd = bid & 7;                 // dispatch round-robins XCDs by bid&7
  const int ord = bid >> 3;                // 0..63
  const int mtile = xcd * 8 + (ord >> 3);  // XCD-exclusive m-panels
  const int ntile = ord & 7;
  const int brow = mtile * BM;
  const int bcol = ntile * BN;

  const int t = threadIdx.x;
  const int lane = t & 63;
  const int w = t >> 6;      // 0..3
  const int wm = w >> 1;     // 0..1
  const int wn = w & 1;      // 0..1

  const unsigned char* xa = ws;            // x tiles: (mt*32+kt)*8192
  const unsigned char* wb = ws + WOFF;     // W tiles: (nt*32+kt)*8192

  // DMA: 4 ops/thread/tile; LDS dest is linear slot*16 (wave-uniform base + lane*16)
#define DMA_TILE(kt, s)                                                    \
  do {                                                                     \
    const unsigned char* ga = xa + (size_t)(mtile * 32 + (kt)) * 8192;     \
    const unsigned char* gb = wb + (size_t)(ntile * 32 + (kt)) * 8192;     \
    dma16(ga + t * 16,         &Lds[s][0][t * 16]);                        \
    dma16(ga + (t + 256) * 16, &Lds[s][0][(t + 256) * 16]);                \
    dma16(gb + t * 16,         &Lds[s][1][t * 16]);                        \
    dma16(gb + (t + 256) * 16, &Lds[s][1][(t + 256) * 16]);                \
  } while (0)

  f32x4 acc[4][4] = {};

  // frag (stripe f): addr = f*1024 + lane*16  -> lane holds row f*16+(l&15),
  // k=(l>>4)*8..+8 (identical fragment contents to v2..v8; layout linear).
#define COMPUTE(s)                                                              \
  do {                                                                          \
    bf16x8 bf[4];                                                               \
    _Pragma("unroll") for (int n = 0; n < 4; ++n)                               \
      bf[n] = __builtin_bit_cast(bf16x8,                                        \
          *(const u16x8*)(&Lds[s][1][(wn * 4 + n) * 1024 + lane * 16]));        \
    bf16x8 am[4];                                                               \
    _Pragma("unroll") for (int m = 0; m < 4; ++m)                               \
      am[m] = __builtin_bit_cast(bf16x8,                                        \
          *(const u16x8*)(&Lds[s][0][(wm * 4 + m) * 1024 + lane * 16]));        \
    __builtin_amdgcn_s_setprio(1);                                              \
    _Pragma("unroll") for (int m = 0; m < 4; ++m)                               \
      _Pragma("unroll") for (int n = 0; n < 4; ++n)                             \
        acc[m][n] = __builtin_amdgcn_mfma_f32_16x16x32_bf16(am[m], bf[n],       \
                                                            acc[m][n], 0, 0, 0);\
    __builtin_amdgcn_s_setprio(0);                                              \
  } while (0)

  // prologue: stage tiles 0,1; wait tile0's 4 DMAs only (tile1's stay in flight)
  DMA_TILE(0, 0);
  DMA_TILE(1, 1);
  asm volatile("s_waitcnt vmcnt(4)" ::: "memory");
  __builtin_amdgcn_sched_barrier(0);
  __builtin_amdgcn_s_barrier();
  __builtin_amdgcn_sched_barrier(0);

  int cs = 0;   // stage holding tile kt
#pragma unroll 1
  for (int kt = 0; kt < NT; ++kt) {
    int ps = cs + 2; if (ps >= 3) ps -= 3;
    if (kt + 2 < NT) DMA_TILE(kt + 2, ps);    // issue 2 tiles ahead
    COMPUTE(cs);
    if (kt + 1 < NT) {
      // ensure tile kt+1's DMAs (issued at kt-1) are complete; keep kt+2's in flight
      if (kt + 2 < NT) { asm volatile("s_waitcnt vmcnt(4)" ::: "memory"); }
      else             { asm volatile("s_waitcnt vmcnt(0)" ::: "memory"); }
      __builtin_amdgcn_sched_barrier(0);
      __builtin_amdgcn_s_barrier();
      __builtin_amdgcn_sched_barrier(0);
    }
    cs = cs + 1; if (cs >= 3) cs = 0;
  }

  // epilogue: C/D layout col = lane&15, row = (lane>>4)*4 + j  [validated v2..v8]
  const int rbase = brow + wm * 64 + ((lane >> 4) << 2);
  const int cbase = bcol + wn * 64 + (lane & 15);
#pragma unroll
  for (int n = 0; n < 4; ++n) {
    const int col = cbase + n * 16;
    const float bv = Bv[col];
#pragma unroll
    for (int m = 0; m < 4; ++m) {
      const int row = rbase + m * 16;
#pragma unroll
      for (int j = 0; j < 4; ++j) {
        C[(size_t)(row + j) * ND + col] = acc[m][n][j] + bv;
      }
    }
  }
}

// ---------------- fallback (ws too small): self-contained staged kernel ------
__global__ __launch_bounds__(256, 2)
void gemm_fallback(const float* __restrict__ X, const float* __restrict__ W,
                   const float* __restrict__ Bv, float* __restrict__ C) {
  __shared__ __align__(16) unsigned char Asm[2][8192];
  __shared__ __align__(16) unsigned char Bsm[2][8192];
  const int bid = blockIdx.x;
  const int brow = (bid >> 3) * BM, bcol = (bid & 7) * BN;
  const int t = threadIdx.x, lane = t & 63, w = t >> 6;
  const int wm = w >> 1, wn = w & 1;
  const int srow = t >> 2, k8 = t & 3;   // slot s = t + j*256 -> row=s>>2, kq=s&3
  const float* gA[2]; const float* gB[2]; int woff[2];
#pragma unroll
  for (int j = 0; j < 2; ++j) {
    int s = t + j * 256, row = s >> 2, kq = s & 3;
    gA[j] = X + (size_t)(brow + row) * KD + kq * 8;
    gB[j] = W + (size_t)(bcol + row) * KD + kq * 8;
    woff[j] = (row >> 4) * 1024 + kq * 256 + (row & 15) * 16;
  }
  f32x4 acc[4][4] = {};
  for (int kt = 0; kt < NT; ++kt) {
    int buf = kt & 1;
#pragma unroll
    for (int j = 0; j < 2; ++j) {
      f32x4 alo = *(const f32x4*)(gA[j] + (size_t)kt * BK);
      f32x4 ahi = *(const f32x4*)(gA[j] + (size_t)kt * BK + 4);
      f32x4 blo = *(const f32x4*)(gB[j] + (size_t)kt * BK);
      f32x4 bhi = *(const f32x4*)(gB[j] + (size_t)kt * BK + 4);
      u16x8 oa, ob;
#pragma unroll
      for (int q = 0; q < 4; ++q) {
        oa[q] = __builtin_bit_cast(unsigned short, (__bf16)alo[q]);
        oa[4+q] = __builtin_bit_cast(unsigned short, (__bf16)ahi[q]);
        ob[q] = __builtin_bit_cast(unsigned short, (__bf16)blo[q]);
        ob[4+q] = __builtin_bit_cast(unsigned short, (__bf16)bhi[q]);
      }
      *(u16x8*)&Asm[buf][woff[j]] = oa;
      *(u16x8*)&Bsm[buf][woff[j]] = ob;
    }
    __syncthreads();
    bf16x8 bf[4], am[4];
#pragma unroll
    for (int n = 0; n < 4; ++n)
      bf[n] = __builtin_bit_cast(bf16x8, *(const u16x8*)(&Bsm[buf][(wn*4+n)*1024 + lane*16]));
#pragma unroll
    for (int m = 0; m < 4; ++m)
      am[m] = __builtin_bit_cast(bf16x8, *(const u16x8*)(&Asm[buf][(wm*4+m)*1024 + lane*16]));
#pragma unroll
    for (int m = 0; m < 4; ++m)
#pragma unroll
      for (int n = 0; n < 4; ++n)
        acc[m][n] = __builtin_amdgcn_mfma_f32_16x16x32_bf16(am[m], bf[n], acc[m][n], 0, 0, 0);
    __syncthreads();
  }
  const int rbase = brow + wm * 64 + ((lane >> 4) << 2);
  const int cbase = bcol + wn * 64 + (lane & 15);
#pragma unroll
  for (int n = 0; n < 4; ++n) {
    const float bv = Bv[cbase + n * 16];
#pragma unroll
    for (int m = 0; m < 4; ++m)
#pragma unroll
      for (int j = 0; j < 4; ++j)
        C[(size_t)(rbase + m * 16 + j) * ND + cbase + n * 16] = acc[m][n][j] + bv;
  }
}

extern "C" void kernel_launch(void* const* d_in, const int* in_sizes, int n_in,
                              void* d_out, int out_size, void* d_ws, size_t ws_size,
                              hipStream_t stream) {
  const float* x = (const float*)d_in[0];   // [8192,1024] f32
  const float* W = (const float*)d_in[1];   // [1024,1024] f32
  const float* b = (const float*)d_in[2];   // [1024] f32
  float* out = (float*)d_out;               // [8192,1024] f32

  if (ws_size >= WS_NEEDED) {
    unsigned char* ws = (unsigned char*)d_ws;
    const int nslots = XSLOTS + WSLOTS;               // 1179648 = 4608 * 256
    hipLaunchKernelGGL(cvt_stage, dim3(nslots / 256), dim3(256), 0, stream, x, W, ws);
    hipLaunchKernelGGL(gemm_dma, dim3((MD / BM) * (ND / BN)), dim3(256), 0, stream,
                       (const unsigned char*)ws, b, out);
  } else {
    hipLaunchKernelGGL(gemm_fallback, dim3((MD / BM) * (ND / BN)), dim3(256), 0,
                       stream, x, W, b, out);
  }
}

// Round 10
// 36.440 us; speedup vs baseline: 1.1398x; 1.1398x over previous
//
#include <hip/hip_runtime.h>
#include <hip/hip_bf16.h>

// out[8192,1024] = x[8192,1024] @ W[1024,1024]^T + b  (fp32 in/out, bf16 MFMA)
// v10 = v6 + ONE change: swapped-operand MFMA accumulate -> transposed C/D
// fragment layout (row = n-dim, col = m-dim), so the epilogue writes f32x4
// (16B) contiguous per lane instead of 4 scalar dwords: 4x fewer store
// instructions, 64B-contiguous row segments. Bias folded as f32x4 add.
// Everything else identical to v6: BM=BN=128, BK=32, 256 thr / 4 waves
// (wave tile 64x64), 2 blocks/CU, depth-2 named-set register prefetch,
// XCD-exclusive m-panels, verified zero-conflict LDS swizzle, __syncthreads.

typedef float f32x4 __attribute__((ext_vector_type(4)));
typedef __bf16 bf16x8 __attribute__((ext_vector_type(8)));
typedef unsigned short u16x4 __attribute__((ext_vector_type(4)));
typedef unsigned short u16x8 __attribute__((ext_vector_type(8)));

#define MD 8192
#define ND 1024
#define KD 1024
#define BM 128
#define BN 128
#define BK 32
#define NT (KD / BK)     // 32 K-steps
#define THREADS 256

__device__ __forceinline__ u16x4 cvt4(f32x4 v) {
  u16x4 o;
#pragma unroll
  for (int i = 0; i < 4; ++i) o[i] = __builtin_bit_cast(unsigned short, (__bf16)v[i]);
  return o;
}

__global__ __launch_bounds__(THREADS, 2)
void linear_mfma_v10(const float* __restrict__ X, const float* __restrict__ W,
                     const float* __restrict__ Bv, float* __restrict__ C) {
  // 16-row stripes of 1024B; within-stripe byte = ((kq<<8)+(r16<<4)+(h<<3)) ^ (kq<<5)
  // (kq=k>>3, h=(k>>2)&1). Verified conflict-free write+read (v3..v8: 0 conflicts).
  __shared__ __align__(16) char Asm[2][BM * BK * 2];   // 8 KB each
  __shared__ __align__(16) char Bsm[2][BN * BK * 2];   // 8 KB each

  const int bid = blockIdx.x;
  const int xcd = bid & 7;                 // dispatch round-robins XCDs by bid&7
  const int ord = bid >> 3;                // 0..63
  const int mtile = xcd * 8 + (ord >> 3);  // 8 XCD-exclusive m-panels per XCD
  const int ntile = ord & 7;
  const int brow = mtile * BM;
  const int bcol = ntile * BN;

  const int t = threadIdx.x;
  const int lane = t & 63;
  const int w = t >> 6;      // 0..3
  const int wm = w >> 1;     // 0..1 : 64-row half
  const int wn = w & 1;      // 0..1 : 64-col half

  // ---- staging map: q = t + i*256 -> (row = q>>3, sc = q&7); f32x4 at k = sc*4
  const float* gA[4];
  const float* gB[4];
  int woff[4];
#pragma unroll
  for (int i = 0; i < 4; ++i) {
    int q = t + i * THREADS;               // 0..1023 -> 128 rows x 8 chunks
    int row = q >> 3, sc = q & 7;
    int kq = sc >> 1, h = sc & 1;
    gA[i] = X + (size_t)(brow + row) * KD + sc * 4;
    gB[i] = W + (size_t)(bcol + row) * KD + sc * 4;
    woff[i] = (row >> 4) * 1024 + ((((kq << 8) + ((row & 15) << 4) + (h << 3))) ^ (kq << 5));
  }

  // fragment read offset within a 1KB stripe (16B/lane, swizzle-mirrored)
  const int fr = (lane * 16) ^ ((lane >> 4) << 5);

  // depth-2 prefetch register sets (literal set index only -> stays in registers)
  f32x4 pa0[4], pb0[4], pa1[4], pb1[4];

#define LOADSET0(kt)                                                      \
  do {                                                                    \
    _Pragma("unroll") for (int i = 0; i < 4; ++i)                         \
        pa0[i] = *(const f32x4*)(gA[i] + (size_t)(kt) * BK);              \
    _Pragma("unroll") for (int i = 0; i < 4; ++i)                         \
        pb0[i] = *(const f32x4*)(gB[i] + (size_t)(kt) * BK);              \
  } while (0)
#define LOADSET1(kt)                                                      \
  do {                                                                    \
    _Pragma("unroll") for (int i = 0; i < 4; ++i)                         \
        pa1[i] = *(const f32x4*)(gA[i] + (size_t)(kt) * BK);              \
    _Pragma("unroll") for (int i = 0; i < 4; ++i)                         \
        pb1[i] = *(const f32x4*)(gB[i] + (size_t)(kt) * BK);              \
  } while (0)

#define WRITESET0(buf)                                                    \
  do {                                                                    \
    _Pragma("unroll") for (int i = 0; i < 4; ++i)                         \
        *(u16x4*)&Asm[buf][woff[i]] = cvt4(pa0[i]);                       \
    _Pragma("unroll") for (int i = 0; i < 4; ++i)                         \
        *(u16x4*)&Bsm[buf][woff[i]] = cvt4(pb0[i]);                       \
  } while (0)
#define WRITESET1(buf)                                                    \
  do {                                                                    \
    _Pragma("unroll") for (int i = 0; i < 4; ++i)                         \
        *(u16x4*)&Asm[buf][woff[i]] = cvt4(pa1[i]);                       \
    _Pragma("unroll") for (int i = 0; i < 4; ++i)                         \
        *(u16x4*)&Bsm[buf][woff[i]] = cvt4(pb1[i]);                       \
  } while (0)

  f32x4 acc[4][4] = {};   // acc[m][n], TRANSPOSED fragment: row|->n-dim, col|->m-dim

#define COMPUTE(buf)                                                           \
  do {                                                                         \
    bf16x8 bf[4];                                                              \
    _Pragma("unroll") for (int n = 0; n < 4; ++n)                              \
      bf[n] = __builtin_bit_cast(bf16x8,                                       \
          *(const u16x8*)(&Bsm[buf][(wn * 4 + n) * 1024 + fr]));               \
    bf16x8 am[4];                                                              \
    _Pragma("unroll") for (int m = 0; m < 4; ++m)                              \
      am[m] = __builtin_bit_cast(bf16x8,                                       \
          *(const u16x8*)(&Asm[buf][(wm * 4 + m) * 1024 + fr]));               \
    __builtin_amdgcn_s_setprio(1);                                             \
    _Pragma("unroll") for (int m = 0; m < 4; ++m)                              \
      _Pragma("unroll") for (int n = 0; n < 4; ++n)                            \
        acc[m][n] = __builtin_amdgcn_mfma_f32_16x16x32_bf16(bf[n], am[m],      \
                                                            acc[m][n], 0, 0, 0); \
    __builtin_amdgcn_s_setprio(0);                                             \
  } while (0)

  // ---- prologue: set0 <- tile0, set1 <- tile1, stage tile0, sync
  LOADSET0(0);
  LOADSET1(1);
  WRITESET0(0);          // waits only set0's loads (counted vmcnt); set1 in flight
  __syncthreads();

  // ---- main loop: 2 K-steps per iteration, one barrier each
#pragma unroll 1
  for (int kt2 = 0; kt2 < NT / 2; ++kt2) {
    // EVEN step kt = 2*kt2 (reads buf0); set0 free -> prefetch tile kt+2
    if (kt2 < NT / 2 - 1) LOADSET0(2 * kt2 + 2);
    COMPUTE(0);
    WRITESET1(1);                          // stage tile kt+1 (loaded 1 step ago)
    __syncthreads();

    // ODD step kt = 2*kt2+1 (reads buf1); set1 free -> prefetch tile kt+3
    if (kt2 < NT / 2 - 1) LOADSET1(2 * kt2 + 3);
    COMPUTE(1);
    if (kt2 < NT / 2 - 1) {
      WRITESET0(0);                        // stage tile kt+2
      __syncthreads();
    }
  }

  // ---- epilogue (transposed fragments): lane owns C row (brow + wm*64 + m*16
  // + (lane&15)) and 4 consecutive cols (bcol + wn*64 + n*16 + (lane>>4)*4 + j)
  // -> one f32x4 store per (m,n). Bias folded as f32x4.
  const int rbase = brow + wm * 64 + (lane & 15);
  const int cbase = bcol + wn * 64 + ((lane >> 4) << 2);
#pragma unroll
  for (int n = 0; n < 4; ++n) {
    const int col = cbase + n * 16;
    const f32x4 bv4 = *(const f32x4*)&Bv[col];
#pragma unroll
    for (int m = 0; m < 4; ++m) {
      const int row = rbase + m * 16;
      f32x4 v = acc[m][n] + bv4;
      *(f32x4*)&C[(size_t)row * ND + col] = v;
    }
  }
}

extern "C" void kernel_launch(void* const* d_in, const int* in_sizes, int n_in,
                              void* d_out, int out_size, void* d_ws, size_t ws_size,
                              hipStream_t stream) {
  const float* x = (const float*)d_in[0];   // [8192,1024] f32
  const float* W = (const float*)d_in[1];   // [1024,1024] f32
  const float* b = (const float*)d_in[2];   // [1024] f32
  float* out = (float*)d_out;               // [8192,1024] f32

  dim3 grid((MD / BM) * (ND / BN));   // 64 * 8 = 512 -> 2 blocks per CU
  dim3 block(THREADS);
  hipLaunchKernelGGL(linear_mfma_v10, grid, block, 0, stream, x, W, b, out);
}

// Round 11
// 35.714 us; speedup vs baseline: 1.1630x; 1.0203x over previous
//
#include <hip/hip_runtime.h>
#include <hip/hip_bf16.h>

// out[8192,1024] = x[8192,1024] @ W[1024,1024]^T + b  (fp32 in/out, bf16 MFMA)
// v11 = v8 + T3 phase interleave: each BK=64 tile split into 2 phases of
// {8 frag ds_reads, 6 global-load issues (tile kt+2), 3 cvt+ds_writes (tile
// kt+1), sched_barrier, setprio 16-MFMA, lgkmcnt(0) + raw s_barrier}.
// vmcnt never drained (counted by construction, loads in flight ~4 phases).
// Geometry/swizzle/epilogue identical to v8: BM=256 x BN=128, BK=64, 512 thr
// / 8 waves as 4Mx2N 64x64, grid 256 = 1 block/CU, XCD-exclusive m-panels.

typedef float f32x4 __attribute__((ext_vector_type(4)));
typedef __bf16 bf16x8 __attribute__((ext_vector_type(8)));
typedef unsigned short u16x8 __attribute__((ext_vector_type(8)));

#define MD 8192
#define ND 1024
#define KD 1024
#define BM 256
#define BN 128
#define BK 64
#define NT (KD / BK)     // 16 K-tiles
#define THREADS 512

__device__ __forceinline__ u16x8 cvt8(f32x4 lo, f32x4 hi) {
  u16x8 o;
#pragma unroll
  for (int j = 0; j < 4; ++j) {
    o[j]     = __builtin_bit_cast(unsigned short, (__bf16)lo[j]);
    o[4 + j] = __builtin_bit_cast(unsigned short, (__bf16)hi[j]);
  }
  return o;
}

// phase-end barrier: own LDS ops drained, raw s_barrier; vmcnt untouched.
#define BAR()                                            \
  do {                                                   \
    asm volatile("s_waitcnt lgkmcnt(0)" ::: "memory");   \
    __builtin_amdgcn_sched_barrier(0);                   \
    __builtin_amdgcn_s_barrier();                        \
    __builtin_amdgcn_sched_barrier(0);                   \
  } while (0)

__global__ __launch_bounds__(THREADS, 2)
void linear_mfma_v11(const float* __restrict__ X, const float* __restrict__ W,
                     const float* __restrict__ Bv, float* __restrict__ C) {
  // LDS tile [rows][64k] bf16, 16-row stripes of 2048B. Slot (row, kslot):
  //   ks=kslot>>2, kq=kslot&3
  //   byte = (row>>4)*2048 + (ks<<10) + (kq<<8) + ((((row&15)^kq^(ks<<2))&15)<<4)
  // v4/v8-measured: 0 bank conflicts (write and frag-read).
  __shared__ __align__(16) char Asm[2][BM * BK * 2];   // 32 KB each
  __shared__ __align__(16) char Bsm[2][BN * BK * 2];   // 16 KB each

  const int bid = blockIdx.x;
  const int xcd = bid & 7;                 // dispatch round-robins XCDs by bid&7
  const int ord = bid >> 3;                // 0..31
  const int mtile = xcd * 4 + (ord >> 3);  // 4 XCD-exclusive m-panels per XCD
  const int ntile = ord & 7;
  const int brow = mtile * BM;
  const int bcol = ntile * BN;

  const int t = threadIdx.x;
  const int lane = t & 63;
  const int w = t >> 6;      // 0..7
  const int wm = w >> 1;     // 0..3 : 64-row quarter of BM=256
  const int wn = w & 1;      // 0..1 : 64-col half of BN=128

  // ---- staging: thread owns 16B k-slots. A: 4/thread, B: 2/thread.
  const int srow = t >> 3;   // 0..63
  const int kslot = t & 7;
  const int ks = kslot >> 2, kq = kslot & 3;

  const float* gA[4]; int woffA[4];
#pragma unroll
  for (int i = 0; i < 4; ++i) {
    int row = srow + i * 64;
    gA[i] = X + (size_t)(brow + row) * KD + kslot * 8;
    woffA[i] = (row >> 4) * 2048 + (ks << 10) + (kq << 8) +
               ((((row & 15) ^ kq ^ (ks << 2)) & 15) << 4);
  }
  const float* gB[2]; int woffB[2];
#pragma unroll
  for (int i = 0; i < 2; ++i) {
    int row = srow + i * 64;
    gB[i] = W + (size_t)(bcol + row) * KD + kslot * 8;
    woffB[i] = (row >> 4) * 2048 + (ks << 10) + (kq << 8) +
               ((((row & 15) ^ kq ^ (ks << 2)) & 15) << 4);
  }

  // fragment read offsets per ks half (lane -> row=lane&15, kq=lane>>4)
  int lb[2];
#pragma unroll
  for (int s = 0; s < 2; ++s)
    lb[s] = (s << 10) + ((lane >> 4) << 8) +
            ((((lane & 15) ^ (lane >> 4) ^ (s << 2)) & 15) << 4);

  // depth-2 prefetch register sets
  f32x4 pa0[8], pb0[4], pa1[8], pb1[4];

  // half h: A chunks i = 2h, 2h+1 ; B chunk i = h   (6 global loads / 3 ds_writes)
#define LOADH(PA, PB, kt, h)                                              \
  do {                                                                    \
    _Pragma("unroll") for (int i = 2 * (h); i < 2 * (h) + 2; ++i) {       \
      const float* p = gA[i] + (size_t)(kt) * BK;                         \
      PA[2 * i] = *(const f32x4*)p;                                       \
      PA[2 * i + 1] = *(const f32x4*)(p + 4);                             \
    }                                                                     \
    {                                                                     \
      const float* p = gB[h] + (size_t)(kt) * BK;                         \
      PB[2 * (h)] = *(const f32x4*)p;                                     \
      PB[2 * (h) + 1] = *(const f32x4*)(p + 4);                           \
    }                                                                     \
  } while (0)

#define WRITEH(PA, PB, buf, h)                                            \
  do {                                                                    \
    _Pragma("unroll") for (int i = 2 * (h); i < 2 * (h) + 2; ++i)         \
        *(u16x8*)&Asm[buf][woffA[i]] = cvt8(PA[2 * i], PA[2 * i + 1]);    \
    *(u16x8*)&Bsm[buf][woffB[h]] = cvt8(PB[2 * (h)], PB[2 * (h) + 1]);    \
  } while (0)

  f32x4 acc[4][4] = {};

  // one phase: frag reads (ks half s of buf) -> [LOAD/WRITE injected between]
#define FRAGS(buf, s)                                                     \
    bf16x8 bf[4], am[4];                                                  \
    _Pragma("unroll") for (int n = 0; n < 4; ++n)                         \
      bf[n] = __builtin_bit_cast(bf16x8,                                  \
          *(const u16x8*)(&Bsm[buf][(wn * 4 + n) * 2048 + lb[s]]));       \
    _Pragma("unroll") for (int m = 0; m < 4; ++m)                         \
      am[m] = __builtin_bit_cast(bf16x8,                                  \
          *(const u16x8*)(&Asm[buf][(wm * 4 + m) * 2048 + lb[s]]));

#define MFMAS()                                                           \
    __builtin_amdgcn_sched_barrier(0);                                    \
    __builtin_amdgcn_s_setprio(1);                                        \
    _Pragma("unroll") for (int m = 0; m < 4; ++m)                         \
      _Pragma("unroll") for (int n = 0; n < 4; ++n)                       \
        acc[m][n] = __builtin_amdgcn_mfma_f32_16x16x32_bf16(am[m], bf[n], \
                                                            acc[m][n], 0, 0, 0); \
    __builtin_amdgcn_s_setprio(0);

  // ---- prologue: set0 <- tile0, set1 <- tile1, stage tile0 -> buf0
  LOADH(pa0, pb0, 0, 0); LOADH(pa0, pb0, 0, 1);
  LOADH(pa1, pb1, 1, 0); LOADH(pa1, pb1, 1, 1);
  WRITEH(pa0, pb0, 0, 0); WRITEH(pa0, pb0, 0, 1);   // counted vmcnt(12)
  BAR();

  // ---- main loop: 2 tiles / 4 phases per iteration; 16 MFMA per phase
#pragma unroll 1
  for (int kt2 = 0; kt2 < NT / 2; ++kt2) {
    const bool pf = (kt2 < NT / 2 - 1);
    {  // EVEN tile (buf0), phase ks=0
      FRAGS(0, 0);
      if (pf) LOADH(pa0, pb0, 2 * kt2 + 2, 0);
      WRITEH(pa1, pb1, 1, 0);                 // tile kt+1 -> buf1, half0
      MFMAS();
      BAR();
    }
    {  // EVEN tile, phase ks=1
      FRAGS(0, 1);
      if (pf) LOADH(pa0, pb0, 2 * kt2 + 2, 1);
      WRITEH(pa1, pb1, 1, 1);                 // tile kt+1 -> buf1, half1
      MFMAS();
      BAR();
    }
    {  // ODD tile (buf1), phase ks=0
      FRAGS(1, 0);
      if (pf) { LOADH(pa1, pb1, 2 * kt2 + 3, 0); WRITEH(pa0, pb0, 0, 0); }
      MFMAS();
      BAR();
    }
    {  // ODD tile, phase ks=1
      FRAGS(1, 1);
      if (pf) { LOADH(pa1, pb1, 2 * kt2 + 3, 1); WRITEH(pa0, pb0, 0, 1); }
      MFMAS();
      BAR();
    }
  }

  // ---- epilogue: C/D layout col = lane&15, row = (lane>>4)*4 + j  [m89, v5-v8]
  const int rbase = brow + wm * 64 + ((lane >> 4) << 2);
  const int cbase = bcol + wn * 64 + (lane & 15);
#pragma unroll
  for (int n = 0; n < 4; ++n) {
    const int col = cbase + n * 16;
    const float bv = Bv[col];
#pragma unroll
    for (int m = 0; m < 4; ++m) {
      const int row = rbase + m * 16;
#pragma unroll
      for (int j = 0; j < 4; ++j) {
        C[(size_t)(row + j) * ND + col] = acc[m][n][j] + bv;
      }
    }
  }
}

extern "C" void kernel_launch(void* const* d_in, const int* in_sizes, int n_in,
                              void* d_out, int out_size, void* d_ws, size_t ws_size,
                              hipStream_t stream) {
  const float* x = (const float*)d_in[0];   // [8192,1024] f32
  const float* W = (const float*)d_in[1];   // [1024,1024] f32
  const float* b = (const float*)d_in[2];   // [1024] f32
  float* out = (float*)d_out;               // [8192,1024] f32

  dim3 grid((MD / BM) * (ND / BN));   // 32 * 8 = 256 blocks = 1 per CU
  dim3 block(THREADS);
  hipLaunchKernelGGL(linear_mfma_v11, grid, block, 0, stream, x, W, b, out);
}